// Round 15
// baseline (719.831 us; speedup 1.0000x reference)
//
#include <hip/hip_runtime.h>
#include <hip/hip_bf16.h>
#include <math.h>

typedef __bf16 bf16_t;
typedef __bf16 bf16x4 __attribute__((ext_vector_type(4)));
typedef __bf16 bf16x8 __attribute__((ext_vector_type(8)));
typedef float f32x4 __attribute__((ext_vector_type(4)));

typedef const __attribute__((address_space(1))) void* gptr_t;
typedef __attribute__((address_space(3))) void* lptr_t;

#define MFMA16(a, b, c) __builtin_amdgcn_mfma_f32_16x16x32_bf16((a), (b), (c), 0, 0, 0)
#define BAR() __builtin_amdgcn_s_barrier()
#define WAIT_LGKM()                                        \
  do {                                                     \
    asm volatile("s_waitcnt lgkmcnt(0)" ::: "memory");     \
    __builtin_amdgcn_sched_barrier(0);                     \
  } while (0)
#define WAIT_VM4()                                         \
  do {                                                     \
    asm volatile("s_waitcnt vmcnt(4)" ::: "memory");       \
    __builtin_amdgcn_sched_barrier(0);                     \
  } while (0)
#define WAIT_VM8()                                         \
  do {                                                     \
    asm volatile("s_waitcnt vmcnt(8)" ::: "memory");       \
    __builtin_amdgcn_sched_barrier(0);                     \
  } while (0)
#define WAIT_VM0()                                         \
  do {                                                     \
    asm volatile("s_waitcnt vmcnt(0)" ::: "memory");       \
    __builtin_amdgcn_sched_barrier(0);                     \
  } while (0)

__device__ __forceinline__ void gload_lds16(const bf16_t* g, bf16_t* l) {
  __builtin_amdgcn_global_load_lds((gptr_t)g, (lptr_t)l, 16, 0, 0);
}

// ---------------------------------------------------------------------------
__global__ __launch_bounds__(256) void conv_kernel(const float* __restrict__ in,
                                                   bf16_t* __restrict__ out, int n4) {
  int i = blockIdx.x * 256 + threadIdx.x;
  if (i >= n4) return;
  float4 v = ((const float4*)in)[i];
  bf16_t* o = out + (size_t)i * 4;
  o[0] = (bf16_t)v.x; o[1] = (bf16_t)v.y; o[2] = (bf16_t)v.z; o[3] = (bf16_t)v.w;
}

// w1 fp32 [8][1024][4096] -> w1t bf16 [8][4096 perm][1024], 64x64 tiles,
// float4 loads + bf16x8 stores.
// perm: a-col c (<2048) -> (c>>5)*64 + (c&31); b-col cb -> (cb>>5)*64 + 32 + (cb&31)
__global__ __launch_bounds__(256) void transp_w1(const float* __restrict__ in,
                                                 bf16_t* __restrict__ out) {
  __shared__ float tile[64][65];
  const float* ip = in + (size_t)blockIdx.z * 1024 * 4096;
  bf16_t* op = out + (size_t)blockIdx.z * 4096 * 1024;
  int t = threadIdx.x;
  int r0 = blockIdx.y * 64, c0 = blockIdx.x * 64;
  int lr = t >> 4, lc4 = (t & 15) * 4;
#pragma unroll
  for (int p = 0; p < 4; ++p) {
    float4 v = *(const float4*)&ip[(size_t)(r0 + p * 16 + lr) * 4096 + c0 + lc4];
    tile[p * 16 + lr][lc4 + 0] = v.x;
    tile[p * 16 + lr][lc4 + 1] = v.y;
    tile[p * 16 + lr][lc4 + 2] = v.z;
    tile[p * 16 + lr][lc4 + 3] = v.w;
  }
  __syncthreads();
  int c = t >> 2, rs = (t & 3) * 16;
  int cg = c0 + c;
  int pc = (cg < 2048) ? ((cg >> 5) * 64 + (cg & 31))
                       : (((cg - 2048) >> 5) * 64 + 32 + ((cg - 2048) & 31));
#pragma unroll
  for (int h = 0; h < 2; ++h) {
    bf16x8 v;
#pragma unroll
    for (int i = 0; i < 8; ++i) v[i] = (bf16_t)tile[rs + h * 8 + i][c];
    *(bf16x8*)&op[(size_t)pc * 1024 + r0 + rs + h * 8] = v;
  }
}

// w2 fp32 [8][2048][1024] -> w2t bf16 [1024][16384]: out[d][e*2048+f] = w2[e][f][d]
__global__ __launch_bounds__(256) void transp_w2(const float* __restrict__ in,
                                                 bf16_t* __restrict__ out) {
  __shared__ float tile[64][65];
  const float* ip = in + (size_t)blockIdx.z * 2048 * 1024;
  int t = threadIdx.x;
  int r0 = blockIdx.y * 64, c0 = blockIdx.x * 64;
  int lr = t >> 4, lc4 = (t & 15) * 4;
#pragma unroll
  for (int p = 0; p < 4; ++p) {
    float4 v = *(const float4*)&ip[(size_t)(r0 + p * 16 + lr) * 1024 + c0 + lc4];
    tile[p * 16 + lr][lc4 + 0] = v.x;
    tile[p * 16 + lr][lc4 + 1] = v.y;
    tile[p * 16 + lr][lc4 + 2] = v.z;
    tile[p * 16 + lr][lc4 + 3] = v.w;
  }
  __syncthreads();
  int c = t >> 2, rs = (t & 3) * 16;
#pragma unroll
  for (int h = 0; h < 2; ++h) {
    bf16x8 v;
#pragma unroll
    for (int i = 0; i < 8; ++i) v[i] = (bf16_t)tile[rs + h * 8 + i][c];
    *(bf16x8*)&out[(size_t)(c0 + c) * 16384 + blockIdx.z * 2048 + r0 + rs + h * 8] = v;
  }
}

// ---------------------------------------------------------------------------
__global__ __launch_bounds__(256) void rmsnorm_kernel(const float* __restrict__ x,
                                                      const float* __restrict__ w,
                                                      bf16_t* __restrict__ out, float eps) {
  int row = blockIdx.x;
  int t = threadIdx.x;
  const float4* xr = (const float4*)(x + (size_t)row * 1024);
  float4 v = xr[t];
  float ss = v.x * v.x + v.y * v.y + v.z * v.z + v.w * v.w;
#pragma unroll
  for (int off = 1; off < 64; off <<= 1) ss += __shfl_xor(ss, off, 64);
  __shared__ float red[4];
  int wave = t >> 6, lane = t & 63;
  if (lane == 0) red[wave] = ss;
  __syncthreads();
  ss = red[0] + red[1] + red[2] + red[3];
  float inv = rsqrtf(ss * (1.0f / 1024.0f) + eps);
  float4 wv = ((const float4*)w)[t];
  bf16_t* o = out + (size_t)row * 1024 + t * 4;
  o[0] = (bf16_t)(v.x * wv.x * inv);
  o[1] = (bf16_t)(v.y * wv.y * inv);
  o[2] = (bf16_t)(v.z * wv.z * inv);
  o[3] = (bf16_t)(v.w * wv.w * inv);
}

// ---------------------------------------------------------------------------
// 128x128x32 GEMM (R2-proven 2-barrier loop) for the small GEMMs, now with
// XCD-chunked block swizzle. EPI 0: bf16 store; 1: fp32 resid+v
template <int EPI>
__global__ __launch_bounds__(256) void gemm_bt(const bf16_t* __restrict__ A,
                                               const bf16_t* __restrict__ Bt,
                                               void* __restrict__ C,
                                               const float* __restrict__ resid,
                                               int M, int N, int K, int lda, int ldb) {
  __shared__ bf16_t As[128 * 32];
  __shared__ bf16_t Bs[128 * 32];
  const int tid = threadIdx.x;
  const int wave = tid >> 6, lane = tid & 63;
  const int gx = gridDim.x;
  int nwg = gx * gridDim.y;
  int lin = blockIdx.x + gx * blockIdx.y;
  int wid = ((nwg & 7) == 0) ? ((lin & 7) * (nwg >> 3) + (lin >> 3)) : lin;
  const int m0 = (wid / gx) * 128, n0 = (wid % gx) * 128;
  const int wr = (wave >> 1) * 64, wc = (wave & 1) * 64;
  const int fr = lane & 15, kg = (lane >> 4) * 8;
  const int srow = lane >> 2, scol = (lane & 3) * 8;

  f32x4 acc[4][4] = {};

  for (int k0 = 0; k0 < K; k0 += 32) {
#pragma unroll
    for (int i = 0; i < 2; ++i) {
      int chunk = wave * 2 + i;
      int row = chunk * 16 + srow;
      gload_lds16(A + (size_t)(m0 + row) * lda + k0 + scol, &As[chunk * 512]);
      gload_lds16(Bt + (size_t)(n0 + row) * ldb + k0 + scol, &Bs[chunk * 512]);
    }
    __syncthreads();
    bf16x8 af[4], bfv[4];
#pragma unroll
    for (int m = 0; m < 4; ++m) af[m] = *(const bf16x8*)&As[(wr + m * 16 + fr) * 32 + kg];
#pragma unroll
    for (int n = 0; n < 4; ++n) bfv[n] = *(const bf16x8*)&Bs[(wc + n * 16 + fr) * 32 + kg];
#pragma unroll
    for (int m = 0; m < 4; ++m)
#pragma unroll
      for (int n = 0; n < 4; ++n) acc[m][n] = MFMA16(af[m], bfv[n], acc[m][n]);
    __syncthreads();
  }

  const int fq = lane >> 4;
#pragma unroll
  for (int m = 0; m < 4; ++m)
#pragma unroll
    for (int n = 0; n < 4; ++n)
#pragma unroll
      for (int j = 0; j < 4; ++j) {
        size_t row = (size_t)(m0 + wr + m * 16 + fq * 4 + j);
        size_t col = (size_t)(n0 + wc + n * 16 + fr);
        float v = acc[m][n][j];
        if (EPI == 0)
          ((bf16_t*)C)[row * N + col] = (bf16_t)v;
        else
          ((float*)C)[row * N + col] = resid[row * N + col] + v;
      }
}

// ---------------------------------------------------------------------------
// 256x256x64 8-phase GEMM (R4/R7 winner) with hoisted LDS offsets and
// pointer-incremented staging (VALU reduction; schedule identical).
// EPI 4: fused SwiGLU->act (z=expert, supertile walk); EPI 5: bf16 slab
template <int EPI>
__global__ __launch_bounds__(512, 2) void gemm256(const bf16_t* __restrict__ A,
                                                  const bf16_t* __restrict__ Bt,
                                                  void* __restrict__ C,
                                                  const float* __restrict__ resid,
                                                  int M, int N, int K, int lda, int ldb) {
  __shared__ bf16_t As[2][256 * 64];
  __shared__ bf16_t Bs[2][256 * 64];
  const int tid = threadIdx.x;
  const int wave = tid >> 6, lane = tid & 63;

  // XCD-chunked swizzle (bijective when nwg % 8 == 0)
  const int gx = gridDim.x, gy = gridDim.y;
  int nwg = gx * gy * gridDim.z;
  int lin = blockIdx.x + gx * (blockIdx.y + gy * blockIdx.z);
  int wid = ((nwg & 7) == 0) ? ((lin & 7) * (nwg >> 3) + (lin >> 3)) : lin;
  int bx, by, bz;
  if (EPI == 4 && gx == 16 && gy == 16 && gridDim.z == 8) {
    int local = wid & 255;
    int st = local >> 4, wi = local & 15;
    bx = (st & 3) * 4 + (wi & 3);
    by = (st >> 2) * 4 + (wi >> 2);
    bz = wid >> 8;
  } else {
    bx = wid % gx;
    by = (wid / gx) % gy;
    bz = wid / (gx * gy);
  }

  const int m0 = by * 256, n0 = bx * 256;
  const int wr = (wave >> 2) * 128, wc = (wave & 3) * 64;
  const int fr = lane & 15, fq = lane >> 4;

  if (EPI == 4) Bt += (size_t)bz * 4096 * 1024;
  if (EPI == 5) {
    A += (size_t)bz * K;
    Bt += (size_t)bz * K;
  }

  // staging pointers: 4 per operand, advanced by 128 elems (2 K-tiles) / iter
  const int srw = lane >> 3;
  const int sgc = (lane & 7) ^ srw;
  const bf16_t* aP[4];
  const bf16_t* bP[4];
#pragma unroll
  for (int i = 0; i < 4; ++i) {
    aP[i] = A + (size_t)(m0 + i * 64 + wave * 8 + srw) * lda + sgc * 8;
    bP[i] = Bt + (size_t)(n0 + i * 64 + wave * 8 + srw) * ldb + sgc * 8;
  }
  bf16_t* aDst[4];
  bf16_t* bDst[4];
#pragma unroll
  for (int i = 0; i < 4; ++i) {
    aDst[i] = &As[0][(i * 64 + wave * 8) * 64];
    bDst[i] = &Bs[0][(i * 64 + wave * 8) * 64];
  }
  const int bufOff = 256 * 64;  // As[1]/Bs[1] offset in elements

  // stage with compile-time buffer and k-offset relative to the running ptrs:
  // koff in {0,64,128,192} elements (tiles t+0..t+3 relative to current base)
  auto stageA = [&](int buf, int koff) {
#pragma unroll
    for (int i = 0; i < 4; ++i) gload_lds16(aP[i] + koff, aDst[i] + buf * bufOff);
  };
  auto stageB = [&](int buf, int koff) {
#pragma unroll
    for (int i = 0; i < 4; ++i) gload_lds16(bP[i] + koff, bDst[i] + buf * bufOff);
  };
  auto advance = [&]() {
#pragma unroll
    for (int i = 0; i < 4; ++i) {
      aP[i] += 128;
      bP[i] += 128;
    }
  };

  f32x4 acc[8][4] = {};
  bf16x8 a_[4][2], b_[4][2];

  // hoisted LDS read offsets (loop-invariant; compile-time indexed)
  int aOff[2][4][2], bOff[2][2][2];
#pragma unroll
  for (int mh = 0; mh < 2; ++mh)
#pragma unroll
    for (int q = 0; q < 4; ++q)
#pragma unroll
      for (int ks = 0; ks < 2; ++ks) {
        int r = wr + mh * 64 + q * 16 + fr;
        aOff[mh][q][ks] = r * 64 + (((fq + ks * 4) ^ (r & 7)) << 3);
      }
#pragma unroll
  for (int nh = 0; nh < 2; ++nh)
#pragma unroll
    for (int q = 0; q < 2; ++q)
#pragma unroll
      for (int ks = 0; ks < 2; ++ks) {
        int r = wc + nh * 32 + q * 16 + fr;
        bOff[nh][q][ks] = r * 64 + (((fq + ks * 4) ^ (r & 7)) << 3);
      }

  auto readA = [&](int b, int mh) {
#pragma unroll
    for (int q = 0; q < 4; ++q)
#pragma unroll
      for (int ks = 0; ks < 2; ++ks)
        a_[q][ks] = *(const bf16x8*)&As[b][aOff[mh][q][ks]];
  };
  auto readB = [&](int b, int nh) {
#pragma unroll
    for (int q = 0; q < 2; ++q)
#pragma unroll
      for (int ks = 0; ks < 2; ++ks)
        b_[nh * 2 + q][ks] = *(const bf16x8*)&Bs[b][bOff[nh][q][ks]];
  };
  auto mfma16x = [&](int mh, int nh) {
    __builtin_amdgcn_s_setprio(1);
#pragma unroll
    for (int q = 0; q < 4; ++q)
#pragma unroll
      for (int n = 0; n < 2; ++n)
#pragma unroll
        for (int ks = 0; ks < 2; ++ks)
          acc[mh * 4 + q][nh * 2 + n] =
              MFMA16(a_[q][ks], b_[nh * 2 + n][ks], acc[mh * 4 + q][nh * 2 + n]);
    __builtin_amdgcn_s_setprio(0);
  };

  const int NKT = K >> 6;
  // prologue: buf0 <- tile 0, buf1 <- tile 1 (koff 0, 64)
  stageB(0, 0);
  stageA(0, 0);
  stageB(1, 64);
  stageA(1, 64);
  WAIT_VM8();  // buf0 landed; buf1's 8 loads in flight
  BAR();
  readA(0, 0);
  readB(0, 0);

  for (int it = 0; it < (NKT >> 1) - 1; ++it) {
    // tiles: buf0 holds t (koff base), buf1 holds t+1; stage t+2 (koff 128),
    // t+3 (koff 192); advance pointers at iteration end.
    // ph1
    WAIT_LGKM(); mfma16x(0, 0); readB(0, 1); BAR();
    // ph2
    WAIT_LGKM(); mfma16x(0, 1); readA(0, 1); BAR();
    // ph3: Bs[0] free -> stage t+2; drain prev buf1 stages
    WAIT_LGKM(); mfma16x(1, 0); stageB(0, 128); WAIT_VM4(); BAR();
    // ph4: As[0] free -> stage t+2; prefetch buf1 operands
    WAIT_LGKM(); mfma16x(1, 1); readA(1, 0); readB(1, 0); stageA(0, 128); BAR();
    // ph5
    WAIT_LGKM(); mfma16x(0, 0); readB(1, 1); BAR();
    // ph6
    WAIT_LGKM(); mfma16x(0, 1); readA(1, 1); BAR();
    // ph7: Bs[1] free -> stage t+3; drain ph3/ph4 stages (buf0)
    WAIT_LGKM(); mfma16x(1, 0); stageB(1, 192); WAIT_VM4(); BAR();
    // ph8: As[1] free -> stage t+3; prefetch buf0 operands
    WAIT_LGKM(); mfma16x(1, 1); readA(0, 0); readB(0, 0); stageA(1, 192); BAR();
    advance();
  }

  // peeled final iteration: no staging
  WAIT_LGKM(); mfma16x(0, 0); readB(0, 1); BAR();
  WAIT_LGKM(); mfma16x(0, 1); readA(0, 1); BAR();
  WAIT_LGKM(); mfma16x(1, 0); WAIT_VM0(); BAR();
  WAIT_LGKM(); mfma16x(1, 1); readA(1, 0); readB(1, 0); BAR();
  WAIT_LGKM(); mfma16x(0, 0); readB(1, 1); BAR();
  WAIT_LGKM(); mfma16x(0, 1); readA(1, 1); BAR();
  WAIT_LGKM(); mfma16x(1, 0); BAR();
  WAIT_LGKM(); mfma16x(1, 1);

  if (EPI == 4) {
    bf16_t* act = (bf16_t*)C;
    int strip = (n0 >> 6) + (wave & 3);
#pragma unroll
    for (int mq = 0; mq < 8; ++mq)
#pragma unroll
      for (int n = 0; n < 2; ++n)
#pragma unroll
        for (int j = 0; j < 4; ++j) {
          size_t row = (size_t)(m0 + wr + mq * 16 + fq * 4 + j);
          size_t col = (size_t)bz * 2048 + strip * 32 + n * 16 + fr;
          float a = acc[mq][n][j], b = acc[mq][n + 2][j];
          act[row * 16384 + col] = (bf16_t)(a * (b / (1.0f + __expf(-b))));
        }
    return;
  }
#pragma unroll
  for (int mq = 0; mq < 8; ++mq)
#pragma unroll
    for (int n = 0; n < 4; ++n)
#pragma unroll
      for (int j = 0; j < 4; ++j) {
        size_t row = (size_t)(m0 + wr + mq * 16 + fq * 4 + j);
        size_t col = (size_t)(n0 + wc + n * 16 + fr);
        float v = acc[mq][n][j];
        if (EPI == 5)
          ((bf16_t*)C + (size_t)bz * M * N)[row * N + col] = (bf16_t)v;
      }
}

// ---------------------------------------------------------------------------
// Flash attention, 128-q-row blocks (8 waves), 64-key tiles, swizzled LDS,
// K/V register prefetch + DOUBLE-BUFFERED K/V LDS -> one barrier per tile.
// Hazards: iter i writes buf[i&1] (from regs holding tile i), sync, computes
// buf[i&1]. Write of buf[i&1] at iter i requires readers of buf[i&1] (iter
// i-2) done: guaranteed by iter i-1's sync. Compute-read of buf[i&1] follows
// this iter's sync after its write. No trailing sync needed.
__global__ __launch_bounds__(512) void attn_kernel(const bf16_t* __restrict__ qkv,
                                                   bf16_t* __restrict__ o) {
  const int S = 1024, LD = 3072;
  int qt = blockIdx.x, bh = blockIdx.y;
  int b = bh >> 4, h = bh & 15;
  int tid = threadIdx.x, wave = tid >> 6, lane = tid & 63;
  int fr = lane & 15, fq = lane >> 4, kg = fq * 8;
  int q0 = qt * 128 + wave * 16;
  const bf16_t* qb = qkv + (size_t)b * S * LD + h * 64;
  const bf16_t* kb = qb + 1024;
  const bf16_t* vb = qb + 2048;

  __shared__ bf16_t Ks[2][64 * 64];
  __shared__ bf16_t Vt[2][64 * 64];
  __shared__ bf16_t Ps[8][16 * 72];

  bf16x8 qf0 = *(const bf16x8*)&qb[(size_t)(q0 + fr) * LD + kg];
  bf16x8 qf1 = *(const bf16x8*)&qb[(size_t)(q0 + fr) * LD + 32 + kg];

  f32x4 acc[4] = {};
  float mrow[4] = {-1e30f, -1e30f, -1e30f, -1e30f};
  float ssum[4] = {0.f, 0.f, 0.f, 0.f};

  int sr = tid >> 3, sch = tid & 7;
  const bf16_t* krow = kb + (size_t)sr * LD + sch * 8;
  const bf16_t* vrow = vb + (size_t)sr * LD + sch * 8;
  bf16x8 kreg = *(const bf16x8*)krow;
  bf16x8 vreg = *(const bf16x8*)vrow;

  int cur = 0;
  for (int k0 = 0; k0 < S; k0 += 64, cur ^= 1) {
    // write staged regs (tile k0) into buf[cur]
    *(bf16x8*)&Ks[cur][sr * 64 + ((sch ^ (sr & 7)) << 3)] = kreg;
#pragma unroll
    for (int i = 0; i < 8; ++i) {
      int d = sch * 8 + i;
      int cs = ((sr >> 3) ^ (d >> 3) ^ (d & 7)) & 7;
      Vt[cur][d * 64 + cs * 8 + (sr & 7)] = vreg[i];
    }
    __syncthreads();
    if (k0 + 64 < S) {
      kreg = *(const bf16x8*)(krow + (size_t)(k0 + 64) * LD);
      vreg = *(const bf16x8*)(vrow + (size_t)(k0 + 64) * LD);
    }

    f32x4 s[4];
#pragma unroll
    for (int kc = 0; kc < 4; ++kc) {
      int row = kc * 16 + fr, sw = row & 7;
      bf16x8 kf0 = *(const bf16x8*)&Ks[cur][row * 64 + ((fq ^ sw) << 3)];
      bf16x8 kf1 = *(const bf16x8*)&Ks[cur][row * 64 + (((4 + fq) ^ sw) << 3)];
      f32x4 z = {};
      z = MFMA16(qf0, kf0, z);
      z = MFMA16(qf1, kf1, z);
      s[kc] = z * 0.125f;
    }
    float pmax[4], psum[4], scl[4];
#pragma unroll
    for (int j = 0; j < 4; ++j)
      pmax[j] = fmaxf(fmaxf(s[0][j], s[1][j]), fmaxf(s[2][j], s[3][j]));
#pragma unroll
    for (int off = 1; off < 16; off <<= 1)
#pragma unroll
      for (int j = 0; j < 4; ++j) pmax[j] = fmaxf(pmax[j], __shfl_xor(pmax[j], off, 64));
#pragma unroll
    for (int j = 0; j < 4; ++j) {
      float nm = fmaxf(mrow[j], pmax[j]);
      scl[j] = __expf(mrow[j] - nm);
      mrow[j] = nm;
      psum[j] = 0.f;
    }
#pragma unroll
    for (int kc = 0; kc < 4; ++kc)
#pragma unroll
      for (int j = 0; j < 4; ++j) {
        float p = __expf(s[kc][j] - mrow[j]);
        psum[j] += p;
        Ps[wave][(fq * 4 + j) * 72 + kc * 16 + fr] = (bf16_t)p;
      }
#pragma unroll
    for (int off = 1; off < 16; off <<= 1)
#pragma unroll
      for (int j = 0; j < 4; ++j) psum[j] += __shfl_xor(psum[j], off, 64);
#pragma unroll
    for (int j = 0; j < 4; ++j) ssum[j] = ssum[j] * scl[j] + psum[j];
#pragma unroll
    for (int n = 0; n < 4; ++n)
#pragma unroll
      for (int j = 0; j < 4; ++j) acc[n][j] *= scl[j];
    asm volatile("s_waitcnt lgkmcnt(0)" ::: "memory");
    bf16x8 pa[2];
#pragma unroll
    for (int ks = 0; ks < 2; ++ks) pa[ks] = *(const bf16x8*)&Ps[wave][fr * 72 + ks * 32 + kg];
#pragma unroll
    for (int n = 0; n < 4; ++n) {
      int d = n * 16 + fr;
      int swd = ((d >> 3) ^ (d & 7)) & 7;
#pragma unroll
      for (int ks = 0; ks < 2; ++ks) {
        bf16x8 vbf = *(const bf16x8*)&Vt[cur][d * 64 + (((ks * 4 + fq) ^ swd) << 3)];
        acc[n] = MFMA16(pa[ks], vbf, acc[n]);
      }
    }
    // no trailing sync: next iter writes buf[cur^1], whose readers finished
    // before THIS iter's sync; Ps is wave-private.
  }
#pragma unroll
  for (int n = 0; n < 4; ++n)
#pragma unroll
    for (int j = 0; j < 4; ++j) {
      size_t row = (size_t)b * S + q0 + fq * 4 + j;
      o[row * 1024 + h * 64 + n * 16 + fr] = (bf16_t)(acc[n][j] / ssum[j]);
    }
}

// ---------------------------------------------------------------------------
__global__ __launch_bounds__(256) void gate_kernel(const bf16_t* __restrict__ hn,
                                                   const float* __restrict__ gw,
                                                   const float* __restrict__ gb,
                                                   const float* __restrict__ grms,
                                                   float* __restrict__ g) {
  int n = blockIdx.x * 4 + (threadIdx.x >> 6);
  int lane = threadIdx.x & 63;
  const bf16_t* xr = hn + (size_t)n * 1024;
  float acc[8] = {};
  for (int i = lane; i < 1024; i += 64) {
    float xv = (float)xr[i];
#pragma unroll
    for (int e = 0; e < 8; ++e) acc[e] += xv * gw[e * 1024 + i];
  }
#pragma unroll
  for (int e = 0; e < 8; ++e)
    for (int off = 1; off < 64; off <<= 1) acc[e] += __shfl_xor(acc[e], off, 64);
  float l[8], ms = 0.f;
#pragma unroll
  for (int e = 0; e < 8; ++e) {
    l[e] = acc[e] + gb[e];
    ms += l[e] * l[e];
  }
  float inv = rsqrtf(ms * 0.125f + 1.1920928955078125e-07f);
  float mx = -1e30f;
#pragma unroll
  for (int e = 0; e < 8; ++e) {
    l[e] = l[e] * inv * grms[e] * 2.0f;
    mx = fmaxf(mx, l[e]);
  }
  float s = 0.f;
#pragma unroll
  for (int e = 0; e < 8; ++e) s += __expf(l[e] - mx);
  float t = 1.0f / s;
  if (lane == 0) g[n] = t / (t + 1e-6f);
}

// ---------------------------------------------------------------------------
// out = x1 + (sum_z moep[z]) * g[row]; 4 bf16 slabs, slab stride Mc*1024 elems
__global__ __launch_bounds__(256) void combine4(const bf16_t* __restrict__ moep,
                                                const float* __restrict__ x1,
                                                const float* __restrict__ g,
                                                float* __restrict__ out, int Mc) {
  size_t i4 = (size_t)blockIdx.x * 256 + threadIdx.x;
  size_t row = i4 >> 8;
  size_t stride = (size_t)Mc * 1024;  // slab stride in elements
  float4 s = {0.f, 0.f, 0.f, 0.f};
#pragma unroll
  for (int z = 0; z < 4; ++z) {
    bf16x4 v = *(const bf16x4*)&moep[z * stride + i4 * 4];
    s.x += (float)v[0]; s.y += (float)v[1]; s.z += (float)v[2]; s.w += (float)v[3];
  }
  float gv = g[row];
  float4 xv = ((const float4*)x1)[i4];
  float4 r;
  r.x = xv.x + s.x * gv;
  r.y = xv.y + s.y * gv;
  r.z = xv.z + s.z * gv;
  r.w = xv.w + s.w * gv;
  ((float4*)out)[i4] = r;
}

// ---------------------------------------------------------------------------
extern "C" void kernel_launch(void* const* d_in, const int* in_sizes, int n_in,
                              void* d_out, int out_size, void* d_ws, size_t ws_size,
                              hipStream_t stream) {
  const float* x = (const float*)d_in[0];
  const float* w_qkv = (const float*)d_in[1];
  const float* w_out = (const float*)d_in[2];
  const float* norm1_w = (const float*)d_in[3];
  const float* norm2_w = (const float*)d_in[4];
  const float* gate_w = (const float*)d_in[5];
  const float* gate_b = (const float*)d_in[6];
  const float* gate_rms = (const float*)d_in[7];
  const float* w1 = (const float*)d_in[8];
  const float* w2 = (const float*)d_in[9];
  float* out = (float*)d_out;

  // chunking: prefer 1 pass (biggest grids); fall back 2 then 4 if ws small
  const size_t baseB = (8ull * 4096 * 1024 + 1024ull * 16384 + 3072ull * 1024 +
                        1024ull * 1024 + 4096ull * 1024) * 2 +
                       4096ull * 1024 * 4 + 4096 * 4;
  int cc = 4;
  if (ws_size >= baseB + 4096ull * 16384 * 2 + 4ull * 4096 * 1024 * 2)
    cc = 1;
  else if (ws_size >= baseB + 2048ull * 16384 * 2 + 4ull * 2048 * 1024 * 2)
    cc = 2;
  const int Mc = 4096 / cc;

  char* ws = (char*)d_ws;
  size_t off = 0;
  auto alloc = [&](size_t bytes) {
    char* p = ws + off;
    off += bytes;
    return p;
  };
  bf16_t* w1t = (bf16_t*)alloc(8ull * 4096 * 1024 * 2);   // [E][4096 perm][1024]
  bf16_t* w2t = (bf16_t*)alloc(1024ull * 16384 * 2);      // [1024][16384]
  bf16_t* wqkvb = (bf16_t*)alloc(3072ull * 1024 * 2);
  bf16_t* woutb = (bf16_t*)alloc(1024ull * 1024 * 2);
  bf16_t* hn = (bf16_t*)alloc(4096ull * 1024 * 2);
  float* x1 = (float*)alloc(4096ull * 1024 * 4);
  float* gbuf = (float*)alloc(4096ull * 4);
  bf16_t* act = (bf16_t*)alloc((size_t)Mc * 16384 * 2);
  bf16_t* moep = (bf16_t*)alloc(4ull * Mc * 1024 * 2);
  bf16_t* qkvb = (bf16_t*)act;    // overlay: dead before MoE
  bf16_t* attno = (bf16_t*)moep;  // overlay: dead before MoE (8MB fits slabs)

  // weight prep
  conv_kernel<<<3072, 256, 0, stream>>>(w_qkv, wqkvb, 3072 * 1024 / 4);
  conv_kernel<<<1024, 256, 0, stream>>>(w_out, woutb, 1024 * 1024 / 4);
  transp_w1<<<dim3(64, 16, 8), 256, 0, stream>>>(w1, w1t);
  transp_w2<<<dim3(16, 32, 8), 256, 0, stream>>>(w2, w2t);

  // attention half
  rmsnorm_kernel<<<4096, 256, 0, stream>>>(x, norm1_w, hn, 1e-8f);
  gemm_bt<0><<<dim3(24, 32), 256, 0, stream>>>(hn, wqkvb, qkvb, nullptr, 4096, 3072, 1024,
                                               1024, 1024);
  attn_kernel<<<dim3(8, 64), 512, 0, stream>>>(qkvb, attno);
  gemm_bt<1><<<dim3(8, 32), 256, 0, stream>>>(attno, woutb, x1, x, 4096, 1024, 1024, 1024,
                                              1024);

  // MoE half
  rmsnorm_kernel<<<4096, 256, 0, stream>>>(x1, norm2_w, hn, 1e-8f);
  gate_kernel<<<1024, 256, 0, stream>>>(hn, gate_w, gate_b, gate_rms, gbuf);
  for (int c = 0; c < cc; ++c) {
    gemm256<4><<<dim3(16, Mc / 256, 8), 512, 0, stream>>>(
        hn + (size_t)c * Mc * 1024, w1t, act, nullptr, Mc, 4096, 1024, 1024, 1024);
    gemm256<5><<<dim3(4, Mc / 256, 4), 512, 0, stream>>>(
        act, w2t, moep, nullptr, Mc, 1024, 4096, 16384, 16384);
    combine4<<<Mc, 256, 0, stream>>>(moep, x1 + (size_t)c * Mc * 1024, gbuf + (size_t)c * Mc,
                                     out + (size_t)c * Mc * 1024, Mc);
  }
}

// Round 16
// 585.766 us; speedup vs baseline: 1.2289x; 1.2289x over previous
//
#include <hip/hip_runtime.h>
#include <hip/hip_bf16.h>
#include <math.h>

typedef __bf16 bf16_t;
typedef __bf16 bf16x4 __attribute__((ext_vector_type(4)));
typedef __bf16 bf16x8 __attribute__((ext_vector_type(8)));
typedef float f32x4 __attribute__((ext_vector_type(4)));

typedef const __attribute__((address_space(1))) void* gptr_t;
typedef __attribute__((address_space(3))) void* lptr_t;

#define MFMA16(a, b, c) __builtin_amdgcn_mfma_f32_16x16x32_bf16((a), (b), (c), 0, 0, 0)
#define BAR() __builtin_amdgcn_s_barrier()
#define WAIT_LGKM()                                        \
  do {                                                     \
    asm volatile("s_waitcnt lgkmcnt(0)" ::: "memory");     \
    __builtin_amdgcn_sched_barrier(0);                     \
  } while (0)
#define WAIT_VM4()                                         \
  do {                                                     \
    asm volatile("s_waitcnt vmcnt(4)" ::: "memory");       \
    __builtin_amdgcn_sched_barrier(0);                     \
  } while (0)
#define WAIT_VM8()                                         \
  do {                                                     \
    asm volatile("s_waitcnt vmcnt(8)" ::: "memory");       \
    __builtin_amdgcn_sched_barrier(0);                     \
  } while (0)
#define WAIT_VM0()                                         \
  do {                                                     \
    asm volatile("s_waitcnt vmcnt(0)" ::: "memory");       \
    __builtin_amdgcn_sched_barrier(0);                     \
  } while (0)

__device__ __forceinline__ void gload_lds16(const bf16_t* g, bf16_t* l) {
  __builtin_amdgcn_global_load_lds((gptr_t)g, (lptr_t)l, 16, 0, 0);
}

// ---------------------------------------------------------------------------
__global__ __launch_bounds__(256) void conv_kernel(const float* __restrict__ in,
                                                   bf16_t* __restrict__ out, int n4) {
  int i = blockIdx.x * 256 + threadIdx.x;
  if (i >= n4) return;
  float4 v = ((const float4*)in)[i];
  bf16_t* o = out + (size_t)i * 4;
  o[0] = (bf16_t)v.x; o[1] = (bf16_t)v.y; o[2] = (bf16_t)v.z; o[3] = (bf16_t)v.w;
}

// w1 fp32 [8][1024][4096] -> w1t bf16 [8][4096 perm][1024], 64x64 tiles,
// float4 loads + bf16x8 stores.
// perm: a-col c (<2048) -> (c>>5)*64 + (c&31); b-col cb -> (cb>>5)*64 + 32 + (cb&31)
__global__ __launch_bounds__(256) void transp_w1(const float* __restrict__ in,
                                                 bf16_t* __restrict__ out) {
  __shared__ float tile[64][65];
  const float* ip = in + (size_t)blockIdx.z * 1024 * 4096;
  bf16_t* op = out + (size_t)blockIdx.z * 4096 * 1024;
  int t = threadIdx.x;
  int r0 = blockIdx.y * 64, c0 = blockIdx.x * 64;
  int lr = t >> 4, lc4 = (t & 15) * 4;
#pragma unroll
  for (int p = 0; p < 4; ++p) {
    float4 v = *(const float4*)&ip[(size_t)(r0 + p * 16 + lr) * 4096 + c0 + lc4];
    tile[p * 16 + lr][lc4 + 0] = v.x;
    tile[p * 16 + lr][lc4 + 1] = v.y;
    tile[p * 16 + lr][lc4 + 2] = v.z;
    tile[p * 16 + lr][lc4 + 3] = v.w;
  }
  __syncthreads();
  int c = t >> 2, rs = (t & 3) * 16;
  int cg = c0 + c;
  int pc = (cg < 2048) ? ((cg >> 5) * 64 + (cg & 31))
                       : (((cg - 2048) >> 5) * 64 + 32 + ((cg - 2048) & 31));
#pragma unroll
  for (int h = 0; h < 2; ++h) {
    bf16x8 v;
#pragma unroll
    for (int i = 0; i < 8; ++i) v[i] = (bf16_t)tile[rs + h * 8 + i][c];
    *(bf16x8*)&op[(size_t)pc * 1024 + r0 + rs + h * 8] = v;
  }
}

// w2 fp32 [8][2048][1024] -> w2t bf16 [1024][16384]: out[d][e*2048+f] = w2[e][f][d]
__global__ __launch_bounds__(256) void transp_w2(const float* __restrict__ in,
                                                 bf16_t* __restrict__ out) {
  __shared__ float tile[64][65];
  const float* ip = in + (size_t)blockIdx.z * 2048 * 1024;
  int t = threadIdx.x;
  int r0 = blockIdx.y * 64, c0 = blockIdx.x * 64;
  int lr = t >> 4, lc4 = (t & 15) * 4;
#pragma unroll
  for (int p = 0; p < 4; ++p) {
    float4 v = *(const float4*)&ip[(size_t)(r0 + p * 16 + lr) * 1024 + c0 + lc4];
    tile[p * 16 + lr][lc4 + 0] = v.x;
    tile[p * 16 + lr][lc4 + 1] = v.y;
    tile[p * 16 + lr][lc4 + 2] = v.z;
    tile[p * 16 + lr][lc4 + 3] = v.w;
  }
  __syncthreads();
  int c = t >> 2, rs = (t & 3) * 16;
#pragma unroll
  for (int h = 0; h < 2; ++h) {
    bf16x8 v;
#pragma unroll
    for (int i = 0; i < 8; ++i) v[i] = (bf16_t)tile[rs + h * 8 + i][c];
    *(bf16x8*)&out[(size_t)(c0 + c) * 16384 + blockIdx.z * 2048 + r0 + rs + h * 8] = v;
  }
}

// ---------------------------------------------------------------------------
__global__ __launch_bounds__(256) void rmsnorm_kernel(const float* __restrict__ x,
                                                      const float* __restrict__ w,
                                                      bf16_t* __restrict__ out, float eps) {
  int row = blockIdx.x;
  int t = threadIdx.x;
  const float4* xr = (const float4*)(x + (size_t)row * 1024);
  float4 v = xr[t];
  float ss = v.x * v.x + v.y * v.y + v.z * v.z + v.w * v.w;
#pragma unroll
  for (int off = 1; off < 64; off <<= 1) ss += __shfl_xor(ss, off, 64);
  __shared__ float red[4];
  int wave = t >> 6, lane = t & 63;
  if (lane == 0) red[wave] = ss;
  __syncthreads();
  ss = red[0] + red[1] + red[2] + red[3];
  float inv = rsqrtf(ss * (1.0f / 1024.0f) + eps);
  float4 wv = ((const float4*)w)[t];
  bf16_t* o = out + (size_t)row * 1024 + t * 4;
  o[0] = (bf16_t)(v.x * wv.x * inv);
  o[1] = (bf16_t)(v.y * wv.y * inv);
  o[2] = (bf16_t)(v.z * wv.z * inv);
  o[3] = (bf16_t)(v.w * wv.w * inv);
}

// ---------------------------------------------------------------------------
// 256x256x64 8-phase GEMM (R4/R7 winner, verbatim best-measured form): one
// barrier per phase, reads issued AFTER the MFMA that frees their register
// slots, stages at ph3/4/7/8, counted vmcnt(4) at ph3/ph7. Peel: no stages,
// vmcnt(0) @ ph3. EPI==4 uses a 4x4 block-supertile walk within each XCD's
// expert (4MB live working set = one XCD L2).
// EPI 0: bf16 store; 1: fp32 resid+v; 4: fused SwiGLU->act (z=expert);
// EPI 5: bf16 slab (z = K-split of 4, K arg = slab length)
template <int EPI>
__global__ __launch_bounds__(512, 2) void gemm256(const bf16_t* __restrict__ A,
                                                  const bf16_t* __restrict__ Bt,
                                                  void* __restrict__ C,
                                                  const float* __restrict__ resid,
                                                  int M, int N, int K, int lda, int ldb) {
  __shared__ bf16_t As[2][256 * 64];
  __shared__ bf16_t Bs[2][256 * 64];
  const int tid = threadIdx.x;
  const int wave = tid >> 6, lane = tid & 63;

  // XCD-chunked swizzle (bijective when nwg % 8 == 0)
  const int gx = gridDim.x, gy = gridDim.y;
  int nwg = gx * gy * gridDim.z;
  int lin = blockIdx.x + gx * (blockIdx.y + gy * blockIdx.z);
  int wid = ((nwg & 7) == 0) ? ((lin & 7) * (nwg >> 3) + (lin >> 3)) : lin;
  int bx, by, bz;
  if (EPI == 4 && gx == 16 && gy == 16 && gridDim.z == 8) {
    // within-XCD 4x4 supertile walk over the 16x16 (bx,by) grid of one expert
    int local = wid & 255;
    int st = local >> 4, wi = local & 15;
    bx = (st & 3) * 4 + (wi & 3);
    by = (st >> 2) * 4 + (wi >> 2);
    bz = wid >> 8;
  } else {
    bx = wid % gx;
    by = (wid / gx) % gy;
    bz = wid / (gx * gy);
  }

  const int m0 = by * 256, n0 = bx * 256;
  const int wr = (wave >> 2) * 128, wc = (wave & 3) * 64;
  const int fr = lane & 15, fq = lane >> 4;

  if (EPI == 4) Bt += (size_t)bz * 4096 * 1024;
  if (EPI == 5) {
    A += (size_t)bz * K;
    Bt += (size_t)bz * K;
  }

  // staging: LDS dest linear (base + lane*16); global source pre-swizzled:
  // chunk_g = (lane&7)^(lane>>3)
  const int srw = lane >> 3;
  const int sgc = (lane & 7) ^ srw;
  const bf16_t* aBase = A + (size_t)(m0 + wave * 8 + srw) * lda + sgc * 8;
  const bf16_t* bBase = Bt + (size_t)(n0 + wave * 8 + srw) * ldb + sgc * 8;

  auto stageA = [&](bf16_t* buf, int kt) {
#pragma unroll
    for (int i = 0; i < 4; ++i) {
      int r = i * 64;
      gload_lds16(aBase + (size_t)r * lda + kt * 64, &buf[(r + wave * 8) * 64]);
    }
  };
  auto stageB = [&](bf16_t* buf, int kt) {
#pragma unroll
    for (int i = 0; i < 4; ++i) {
      int r = i * 64;
      gload_lds16(bBase + (size_t)r * ldb + kt * 64, &buf[(r + wave * 8) * 64]);
    }
  };

  f32x4 acc[8][4] = {};
  bf16x8 a_[4][2], b_[4][2];

  // swizzled read: row r, k-group (fq + ks*4): chunk = (fq+ks*4) ^ (r&7)
  auto readA = [&](int b, int mh) {
#pragma unroll
    for (int q = 0; q < 4; ++q)
#pragma unroll
      for (int ks = 0; ks < 2; ++ks) {
        int r = wr + mh * 64 + q * 16 + fr;
        a_[q][ks] = *(const bf16x8*)&As[b][r * 64 + (((fq + ks * 4) ^ (fr & 7)) << 3)];
      }
  };
  auto readB = [&](int b, int nh) {
#pragma unroll
    for (int q = 0; q < 2; ++q)
#pragma unroll
      for (int ks = 0; ks < 2; ++ks) {
        int r = wc + nh * 32 + q * 16 + fr;
        b_[nh * 2 + q][ks] = *(const bf16x8*)&Bs[b][r * 64 + (((fq + ks * 4) ^ (fr & 7)) << 3)];
      }
  };
  auto mfma16x = [&](int mh, int nh) {
    __builtin_amdgcn_s_setprio(1);
#pragma unroll
    for (int q = 0; q < 4; ++q)
#pragma unroll
      for (int n = 0; n < 2; ++n)
#pragma unroll
        for (int ks = 0; ks < 2; ++ks)
          acc[mh * 4 + q][nh * 2 + n] =
              MFMA16(a_[q][ks], b_[nh * 2 + n][ks], acc[mh * 4 + q][nh * 2 + n]);
    __builtin_amdgcn_s_setprio(0);
  };

  const int NKT = K >> 6;
  // prologue: stage buf0 (tile 0) fully, then buf1 (tile 1) fully
  stageB(Bs[0], 0);
  stageA(As[0], 0);
  stageB(Bs[1], 1);
  stageA(As[1], 1);
  WAIT_VM8();  // buf0 landed; buf1's 8 loads in flight
  BAR();
  readA(0, 0);  // initial operand batch for ph1
  readB(0, 0);

  for (int it = 0; it < (NKT >> 1) - 1; ++it) {
    const int t2 = 2 * it + 2, t3 = 2 * it + 3;
    // ph1
    WAIT_LGKM(); mfma16x(0, 0); readB(0, 1); BAR();
    // ph2
    WAIT_LGKM(); mfma16x(0, 1); readA(0, 1); BAR();
    // ph3: Bs[0] free (reads drained ph2-top) -> stage t2; drain prev buf1 stages
    WAIT_LGKM(); mfma16x(1, 0); stageB(Bs[0], t2); WAIT_VM4(); BAR();
    // ph4: As[0] free -> stage t2; prefetch buf1 operands
    WAIT_LGKM(); mfma16x(1, 1); readA(1, 0); readB(1, 0); stageA(As[0], t2); BAR();
    // ph5
    WAIT_LGKM(); mfma16x(0, 0); readB(1, 1); BAR();
    // ph6
    WAIT_LGKM(); mfma16x(0, 1); readA(1, 1); BAR();
    // ph7: Bs[1] free -> stage t3; drain ph3/ph4 stages (buf0-t2)
    WAIT_LGKM(); mfma16x(1, 0); stageB(Bs[1], t3); WAIT_VM4(); BAR();
    // ph8: As[1] free -> stage t3; prefetch buf0-t2 operands
    WAIT_LGKM(); mfma16x(1, 1); readA(0, 0); readB(0, 0); stageA(As[1], t3); BAR();
  }

  // peeled final iteration: no staging
  WAIT_LGKM(); mfma16x(0, 0); readB(0, 1); BAR();
  WAIT_LGKM(); mfma16x(0, 1); readA(0, 1); BAR();
  WAIT_LGKM(); mfma16x(1, 0); WAIT_VM0(); BAR();
  WAIT_LGKM(); mfma16x(1, 1); readA(1, 0); readB(1, 0); BAR();
  WAIT_LGKM(); mfma16x(0, 0); readB(1, 1); BAR();
  WAIT_LGKM(); mfma16x(0, 1); readA(1, 1); BAR();
  WAIT_LGKM(); mfma16x(1, 0); BAR();
  WAIT_LGKM(); mfma16x(1, 1);

  if (EPI == 4) {
    bf16_t* act = (bf16_t*)C;
    int strip = (n0 >> 6) + (wave & 3);
#pragma unroll
    for (int mq = 0; mq < 8; ++mq)
#pragma unroll
      for (int n = 0; n < 2; ++n)
#pragma unroll
        for (int j = 0; j < 4; ++j) {
          size_t row = (size_t)(m0 + wr + mq * 16 + fq * 4 + j);
          size_t col = (size_t)bz * 2048 + strip * 32 + n * 16 + fr;
          float a = acc[mq][n][j], b = acc[mq][n + 2][j];
          act[row * 16384 + col] = (bf16_t)(a * (b / (1.0f + __expf(-b))));
        }
    return;
  }
#pragma unroll
  for (int mq = 0; mq < 8; ++mq)
#pragma unroll
    for (int n = 0; n < 4; ++n)
#pragma unroll
      for (int j = 0; j < 4; ++j) {
        size_t row = (size_t)(m0 + wr + mq * 16 + fq * 4 + j);
        size_t col = (size_t)(n0 + wc + n * 16 + fr);
        float v = acc[mq][n][j];
        if (EPI == 0)
          ((bf16_t*)C)[row * N + col] = (bf16_t)v;
        else if (EPI == 1)
          ((float*)C)[row * N + col] = resid[row * N + col] + v;
        else if (EPI == 5)
          ((bf16_t*)C + (size_t)bz * M * N)[row * N + col] = (bf16_t)v;
      }
}

// ---------------------------------------------------------------------------
// Flash attention, 128-q-row blocks (8 waves), 64-key tiles, swizzled LDS,
// K/V register double-buffer (single LDS buffer, two barriers per tile).
__global__ __launch_bounds__(512) void attn_kernel(const bf16_t* __restrict__ qkv,
                                                   bf16_t* __restrict__ o) {
  const int S = 1024, LD = 3072;
  int qt = blockIdx.x, bh = blockIdx.y;
  int b = bh >> 4, h = bh & 15;
  int tid = threadIdx.x, wave = tid >> 6, lane = tid & 63;
  int fr = lane & 15, fq = lane >> 4, kg = fq * 8;
  int q0 = qt * 128 + wave * 16;
  const bf16_t* qb = qkv + (size_t)b * S * LD + h * 64;
  const bf16_t* kb = qb + 1024;
  const bf16_t* vb = qb + 2048;

  __shared__ bf16_t Ks[64 * 64];
  __shared__ bf16_t Vt[64 * 64];
  __shared__ bf16_t Ps[8][16 * 72];

  bf16x8 qf0 = *(const bf16x8*)&qb[(size_t)(q0 + fr) * LD + kg];
  bf16x8 qf1 = *(const bf16x8*)&qb[(size_t)(q0 + fr) * LD + 32 + kg];

  f32x4 acc[4] = {};
  float mrow[4] = {-1e30f, -1e30f, -1e30f, -1e30f};
  float ssum[4] = {0.f, 0.f, 0.f, 0.f};

  int sr = tid >> 3, sch = tid & 7;
  const bf16_t* krow = kb + (size_t)sr * LD + sch * 8;
  const bf16_t* vrow = vb + (size_t)sr * LD + sch * 8;
  bf16x8 kreg = *(const bf16x8*)krow;
  bf16x8 vreg = *(const bf16x8*)vrow;

  for (int k0 = 0; k0 < S; k0 += 64) {
    *(bf16x8*)&Ks[sr * 64 + ((sch ^ (sr & 7)) << 3)] = kreg;
#pragma unroll
    for (int i = 0; i < 8; ++i) {
      int d = sch * 8 + i;
      int cs = ((sr >> 3) ^ (d >> 3) ^ (d & 7)) & 7;
      Vt[d * 64 + cs * 8 + (sr & 7)] = vreg[i];
    }
    __syncthreads();
    if (k0 + 64 < S) {
      kreg = *(const bf16x8*)(krow + (size_t)(k0 + 64) * LD);
      vreg = *(const bf16x8*)(vrow + (size_t)(k0 + 64) * LD);
    }

    f32x4 s[4];
#pragma unroll
    for (int kc = 0; kc < 4; ++kc) {
      int row = kc * 16 + fr, sw = row & 7;
      bf16x8 kf0 = *(const bf16x8*)&Ks[row * 64 + ((fq ^ sw) << 3)];
      bf16x8 kf1 = *(const bf16x8*)&Ks[row * 64 + (((4 + fq) ^ sw) << 3)];
      f32x4 z = {};
      z = MFMA16(qf0, kf0, z);
      z = MFMA16(qf1, kf1, z);
      s[kc] = z * 0.125f;
    }
    float pmax[4], psum[4], scl[4];
#pragma unroll
    for (int j = 0; j < 4; ++j)
      pmax[j] = fmaxf(fmaxf(s[0][j], s[1][j]), fmaxf(s[2][j], s[3][j]));
#pragma unroll
    for (int off = 1; off < 16; off <<= 1)
#pragma unroll
      for (int j = 0; j < 4; ++j) pmax[j] = fmaxf(pmax[j], __shfl_xor(pmax[j], off, 64));
#pragma unroll
    for (int j = 0; j < 4; ++j) {
      float nm = fmaxf(mrow[j], pmax[j]);
      scl[j] = __expf(mrow[j] - nm);
      mrow[j] = nm;
      psum[j] = 0.f;
    }
#pragma unroll
    for (int kc = 0; kc < 4; ++kc)
#pragma unroll
      for (int j = 0; j < 4; ++j) {
        float p = __expf(s[kc][j] - mrow[j]);
        psum[j] += p;
        Ps[wave][(fq * 4 + j) * 72 + kc * 16 + fr] = (bf16_t)p;
      }
#pragma unroll
    for (int off = 1; off < 16; off <<= 1)
#pragma unroll
      for (int j = 0; j < 4; ++j) psum[j] += __shfl_xor(psum[j], off, 64);
#pragma unroll
    for (int j = 0; j < 4; ++j) ssum[j] = ssum[j] * scl[j] + psum[j];
#pragma unroll
    for (int n = 0; n < 4; ++n)
#pragma unroll
      for (int j = 0; j < 4; ++j) acc[n][j] *= scl[j];
    asm volatile("s_waitcnt lgkmcnt(0)" ::: "memory");
    bf16x8 pa[2];
#pragma unroll
    for (int ks = 0; ks < 2; ++ks) pa[ks] = *(const bf16x8*)&Ps[wave][fr * 72 + ks * 32 + kg];
#pragma unroll
    for (int n = 0; n < 4; ++n) {
      int d = n * 16 + fr;
      int swd = ((d >> 3) ^ (d & 7)) & 7;
#pragma unroll
      for (int ks = 0; ks < 2; ++ks) {
        bf16x8 vbf = *(const bf16x8*)&Vt[d * 64 + (((ks * 4 + fq) ^ swd) << 3)];
        acc[n] = MFMA16(pa[ks], vbf, acc[n]);
      }
    }
    __syncthreads();
  }
#pragma unroll
  for (int n = 0; n < 4; ++n)
#pragma unroll
    for (int j = 0; j < 4; ++j) {
      size_t row = (size_t)b * S + q0 + fq * 4 + j;
      o[row * 1024 + h * 64 + n * 16 + fr] = (bf16_t)(acc[n][j] / ssum[j]);
    }
}

// ---------------------------------------------------------------------------
__global__ __launch_bounds__(256) void gate_kernel(const bf16_t* __restrict__ hn,
                                                   const float* __restrict__ gw,
                                                   const float* __restrict__ gb,
                                                   const float* __restrict__ grms,
                                                   float* __restrict__ g) {
  int n = blockIdx.x * 4 + (threadIdx.x >> 6);
  int lane = threadIdx.x & 63;
  const bf16_t* xr = hn + (size_t)n * 1024;
  float acc[8] = {};
  for (int i = lane; i < 1024; i += 64) {
    float xv = (float)xr[i];
#pragma unroll
    for (int e = 0; e < 8; ++e) acc[e] += xv * gw[e * 1024 + i];
  }
#pragma unroll
  for (int e = 0; e < 8; ++e)
    for (int off = 1; off < 64; off <<= 1) acc[e] += __shfl_xor(acc[e], off, 64);
  float l[8], ms = 0.f;
#pragma unroll
  for (int e = 0; e < 8; ++e) {
    l[e] = acc[e] + gb[e];
    ms += l[e] * l[e];
  }
  float inv = rsqrtf(ms * 0.125f + 1.1920928955078125e-07f);
  float mx = -1e30f;
#pragma unroll
  for (int e = 0; e < 8; ++e) {
    l[e] = l[e] * inv * grms[e] * 2.0f;
    mx = fmaxf(mx, l[e]);
  }
  float s = 0.f;
#pragma unroll
  for (int e = 0; e < 8; ++e) s += __expf(l[e] - mx);
  float t = 1.0f / s;
  if (lane == 0) g[n] = t / (t + 1e-6f);
}

// ---------------------------------------------------------------------------
// out = x1 + (sum_z moep[z]) * g[row]; 4 bf16 slabs, slab stride Mc*1024 elems
__global__ __launch_bounds__(256) void combine4(const bf16_t* __restrict__ moep,
                                                const float* __restrict__ x1,
                                                const float* __restrict__ g,
                                                float* __restrict__ out, int Mc) {
  size_t i4 = (size_t)blockIdx.x * 256 + threadIdx.x;
  size_t row = i4 >> 8;
  size_t stride = (size_t)Mc * 1024;  // slab stride in elements
  float4 s = {0.f, 0.f, 0.f, 0.f};
#pragma unroll
  for (int z = 0; z < 4; ++z) {
    bf16x4 v = *(const bf16x4*)&moep[z * stride + i4 * 4];
    s.x += (float)v[0]; s.y += (float)v[1]; s.z += (float)v[2]; s.w += (float)v[3];
  }
  float gv = g[row];
  float4 xv = ((const float4*)x1)[i4];
  float4 r;
  r.x = xv.x + s.x * gv;
  r.y = xv.y + s.y * gv;
  r.z = xv.z + s.z * gv;
  r.w = xv.w + s.w * gv;
  ((float4*)out)[i4] = r;
}

// ---------------------------------------------------------------------------
extern "C" void kernel_launch(void* const* d_in, const int* in_sizes, int n_in,
                              void* d_out, int out_size, void* d_ws, size_t ws_size,
                              hipStream_t stream) {
  const float* x = (const float*)d_in[0];
  const float* w_qkv = (const float*)d_in[1];
  const float* w_out = (const float*)d_in[2];
  const float* norm1_w = (const float*)d_in[3];
  const float* norm2_w = (const float*)d_in[4];
  const float* gate_w = (const float*)d_in[5];
  const float* gate_b = (const float*)d_in[6];
  const float* gate_rms = (const float*)d_in[7];
  const float* w1 = (const float*)d_in[8];
  const float* w2 = (const float*)d_in[9];
  float* out = (float*)d_out;

  // chunking: prefer 1 pass (biggest grids); fall back 2 then 4 if ws small
  const size_t baseB = (8ull * 4096 * 1024 + 1024ull * 16384 + 3072ull * 1024 +
                        1024ull * 1024 + 4096ull * 1024) * 2 +
                       4096ull * 1024 * 4 + 4096 * 4;
  int cc = 4;
  if (ws_size >= baseB + 4096ull * 16384 * 2 + 4ull * 4096 * 1024 * 2)
    cc = 1;
  else if (ws_size >= baseB + 2048ull * 16384 * 2 + 4ull * 2048 * 1024 * 2)
    cc = 2;
  const int Mc = 4096 / cc;

  char* ws = (char*)d_ws;
  size_t off = 0;
  auto alloc = [&](size_t bytes) {
    char* p = ws + off;
    off += bytes;
    return p;
  };
  bf16_t* w1t = (bf16_t*)alloc(8ull * 4096 * 1024 * 2);   // [E][4096 perm][1024]
  bf16_t* w2t = (bf16_t*)alloc(1024ull * 16384 * 2);      // [1024][16384]
  bf16_t* wqkvb = (bf16_t*)alloc(3072ull * 1024 * 2);
  bf16_t* woutb = (bf16_t*)alloc(1024ull * 1024 * 2);
  bf16_t* hn = (bf16_t*)alloc(4096ull * 1024 * 2);
  float* x1 = (float*)alloc(4096ull * 1024 * 4);
  float* gbuf = (float*)alloc(4096ull * 4);
  bf16_t* act = (bf16_t*)alloc((size_t)Mc * 16384 * 2);
  bf16_t* moep = (bf16_t*)alloc(4ull * Mc * 1024 * 2);
  bf16_t* qkvb = (bf16_t*)act;    // overlay: dead before MoE
  bf16_t* attno = (bf16_t*)moep;  // overlay: dead before MoE (8MB fits slabs)

  // weight prep
  conv_kernel<<<3072, 256, 0, stream>>>(w_qkv, wqkvb, 3072 * 1024 / 4);
  conv_kernel<<<1024, 256, 0, stream>>>(w_out, woutb, 1024 * 1024 / 4);
  transp_w1<<<dim3(64, 16, 8), 256, 0, stream>>>(w1, w1t);
  transp_w2<<<dim3(16, 32, 8), 256, 0, stream>>>(w2, w2t);

  // attention half
  rmsnorm_kernel<<<4096, 256, 0, stream>>>(x, norm1_w, hn, 1e-8f);
  gemm256<0><<<dim3(12, 16), 512, 0, stream>>>(hn, wqkvb, qkvb, nullptr, 4096, 3072, 1024,
                                               1024, 1024);
  attn_kernel<<<dim3(8, 64), 512, 0, stream>>>(qkvb, attno);
  gemm256<1><<<dim3(4, 16), 512, 0, stream>>>(attno, woutb, x1, x, 4096, 1024, 1024, 1024,
                                              1024);

  // MoE half
  rmsnorm_kernel<<<4096, 256, 0, stream>>>(x1, norm2_w, hn, 1e-8f);
  gate_kernel<<<1024, 256, 0, stream>>>(hn, gate_w, gate_b, gate_rms, gbuf);
  for (int c = 0; c < cc; ++c) {
    gemm256<4><<<dim3(16, Mc / 256, 8), 512, 0, stream>>>(
        hn + (size_t)c * Mc * 1024, w1t, act, nullptr, Mc, 4096, 1024, 1024, 1024);
    gemm256<5><<<dim3(4, Mc / 256, 4), 512, 0, stream>>>(
        act, w2t, moep, nullptr, Mc, 1024, 4096, 16384, 16384);
    combine4<<<Mc, 256, 0, stream>>>(moep, x1 + (size_t)c * Mc * 1024, gbuf + (size_t)c * Mc,
                                     out + (size_t)c * Mc * 1024, Mc);
  }
}